// Round 2
// baseline (127.681 us; speedup 1.0000x reference)
//
#include <hip/hip_runtime.h>

// Problem constants: D=32, H=64, O=1, T=1024, M=8, N=32768
#define DD 32
#define HH 64
#define TT 1024
#define MM 8
#define NN 32768
#define SS 2177              // H*D + H + O*H + O
#define SP 2180              // padded states row stride (floats), 16B-aligned rows

// ws layout (bytes):
//   [0,      4096)   counts  int[1024]
//   [4096,   8192)   cursor  int[1024]   (primed to bucket starts by scan)
//   [8192, 139264)   perm    int[32768]
//   [139264, +~8.93MB) states float[TT*SP]
#define WS_COUNTS 0
#define WS_CURSOR 4096
#define WS_PERM   8192
#define WS_STATES 139264

__global__ __launch_bounds__(256) void hist_kernel(
    const int* __restrict__ ticker, int* __restrict__ counts)
{
    int n = blockIdx.x * 256 + threadIdx.x;
    atomicAdd(&counts[ticker[n]], 1);
}

// Single block, 1024 threads: exclusive scan of counts -> cursor (bucket starts)
__global__ __launch_bounds__(1024) void scan_kernel(
    const int* __restrict__ counts, int* __restrict__ cursor)
{
    __shared__ int sc[TT];
    int tid = threadIdx.x;
    int c = counts[tid];
    sc[tid] = c;
    __syncthreads();
#pragma unroll
    for (int off = 1; off < TT; off <<= 1) {
        int v = (tid >= off) ? sc[tid - off] : 0;
        __syncthreads();
        sc[tid] += v;
        __syncthreads();
    }
    cursor[tid] = sc[tid] - c;   // exclusive
}

__global__ __launch_bounds__(256) void scatter_kernel(
    const int* __restrict__ ticker, int* __restrict__ cursor, int* __restrict__ perm)
{
    int n = blockIdx.x * 256 + threadIdx.x;
    int t = ticker[n];
    int pos = atomicAdd(&cursor[t], 1);
    perm[pos] = n;
}

// states[t][s] = base[s] + bias[s] + sum_m meta_w[s][m] * mesa[m][t]
__global__ __launch_bounds__(256) void states_kernel(
    const float* __restrict__ mesa,   // (M, T)
    const float* __restrict__ metaw,  // (S, M)
    const float* __restrict__ metab,  // (S,)
    const float* __restrict__ base,   // (S,)
    float* __restrict__ states)       // (T, SP)
{
    int s = blockIdx.x * 256 + threadIdx.x;
    int t = blockIdx.y;
    if (s >= SS) return;
    const float4* mw = (const float4*)(metaw + s * MM);
    float4 a = mw[0], b = mw[1];
    float acc = base[s] + metab[s];
    acc = fmaf(a.x, mesa[0 * TT + t], acc);
    acc = fmaf(a.y, mesa[1 * TT + t], acc);
    acc = fmaf(a.z, mesa[2 * TT + t], acc);
    acc = fmaf(a.w, mesa[3 * TT + t], acc);
    acc = fmaf(b.x, mesa[4 * TT + t], acc);
    acc = fmaf(b.y, mesa[5 * TT + t], acc);
    acc = fmaf(b.z, mesa[6 * TT + t], acc);
    acc = fmaf(b.w, mesa[7 * TT + t], acc);
    states[(size_t)t * SP + s] = acc;
}

// One wave per (sorted) sample; 16 waves/block so a block's waves mostly share
// one ticker -> w1 row hits L1 after the first wave touches it.
__global__ __launch_bounds__(1024) void mlp_kernel(
    const float* __restrict__ x,       // (N, D)
    const int*   __restrict__ ticker,  // (N,)
    const int*   __restrict__ perm,    // (N,) sorted-by-ticker sample ids
    const float* __restrict__ states,  // (T, SP)
    float* __restrict__ out)           // (N, 1)
{
    int wave = threadIdx.x >> 6;
    int lane = threadIdx.x & 63;
    int idx = blockIdx.x * 16 + wave;

    int n = perm[idx];
    int t = ticker[n];
    const float* row = states + (size_t)t * SP;

    float xv = (lane < DD) ? x[n * DD + lane] : 0.0f;

    const float4* wp = (const float4*)(row + lane * DD);
    float h = 0.0f;
#pragma unroll
    for (int q = 0; q < 8; ++q) {
        float4 w = wp[q];
        h = fmaf(__shfl(xv, 4 * q + 0, 64), w.x, h);
        h = fmaf(__shfl(xv, 4 * q + 1, 64), w.y, h);
        h = fmaf(__shfl(xv, 4 * q + 2, 64), w.z, h);
        h = fmaf(__shfl(xv, 4 * q + 3, 64), w.w, h);
    }
    h += row[HH * DD + lane];          // b1
    h = fmaxf(h, 0.0f);                // relu

    float p = h * row[HH * DD + HH + lane];  // * w2
#pragma unroll
    for (int off = 32; off >= 1; off >>= 1)
        p += __shfl_down(p, off, 64);

    if (lane == 0)
        out[n] = p + row[HH * DD + HH + HH];  // + b2
}

extern "C" void kernel_launch(void* const* d_in, const int* in_sizes, int n_in,
                              void* d_out, int out_size, void* d_ws, size_t ws_size,
                              hipStream_t stream) {
    const float* x      = (const float*)d_in[0];
    const int*   ticker = (const int*)  d_in[1];
    const float* mesa   = (const float*)d_in[2];
    const float* metaw  = (const float*)d_in[3];
    const float* metab  = (const float*)d_in[4];
    const float* base   = (const float*)d_in[5];
    float* out = (float*)d_out;

    char* ws = (char*)d_ws;
    int*   counts = (int*)(ws + WS_COUNTS);
    int*   cursor = (int*)(ws + WS_CURSOR);
    int*   perm   = (int*)(ws + WS_PERM);
    float* states = (float*)(ws + WS_STATES);

    hipMemsetAsync(counts, 0, TT * sizeof(int), stream);
    hist_kernel<<<NN / 256, 256, 0, stream>>>(ticker, counts);
    scan_kernel<<<1, 1024, 0, stream>>>(counts, cursor);
    scatter_kernel<<<NN / 256, 256, 0, stream>>>(ticker, cursor, perm);

    dim3 g1((SS + 255) / 256, TT);
    states_kernel<<<g1, 256, 0, stream>>>(mesa, metaw, metab, base, states);

    mlp_kernel<<<NN / 16, 1024, 0, stream>>>(x, ticker, perm, states, out);
}

// Round 3
// 86.858 us; speedup vs baseline: 1.4700x; 1.4700x over previous
//
#include <hip/hip_runtime.h>

// D=32, H=64, O=1, T=1024, M=8, N=32768, S=2177
// Factorization: states[t][s] = B[s] + sum_m U[s][m]*mesa[m][t],
//   B = base_state + meta_bias, U = meta_layer_weight.
// h[n][j] = relu( sum_d x[d]*B[j*32+d] + sum_m mesa[m][t]*( sum_d x[d]*U[j*32+d][m] ) + b1(t,j) )
// -> per-sample g[j][m] = sum_d x[d]*U[j*32+d][m] is ticker-independent: fuse in registers.

#define DD 32
#define TT 1024
#define MM 8
#define KB 8   // samples per wave

__global__ __launch_bounds__(1024, 4) void fused_kernel(
    const float* __restrict__ x,       // (N,32)
    const int*   __restrict__ ticker,  // (N,)
    const float* __restrict__ mesa,    // (8,1024)
    const float* __restrict__ metaw,   // (2177,8)
    const float* __restrict__ metab,   // (2177,)
    const float* __restrict__ base,    // (2177,)
    float* __restrict__ out)           // (N,1)
{
    // LDS: 64 KB + 8 KB + 2 KB + 2 KB + 512 B = 76.5 KB -> 1-2 blocks/CU
    __shared__ float4 U4[32 * 2 * 64];   // [d][m4][j] : metaw[(j*32+d)*8 + m4*4 ..]
    __shared__ float4 B1q[8 * 64];       // [dq][j]    : B[j*32 + dq*4 ..]
    __shared__ float4 Ub1[2 * 64];       // [m4][j]    : metaw[(2048+j)*8 + m4*4 ..]
    __shared__ float4 U2q[2 * 64];       // [m4][j]    : metaw[(2112+j)*8 + m4*4 ..]
    __shared__ float  B1b[64];           // B[2048+j]
    __shared__ float  B2b[64];           // B[2112+j]

    const int tid  = threadIdx.x;
    const int lane = tid & 63;           // j
    const int dm   = tid >> 6;           // wave id, 0..15

    // ---- stage (one-time per block; LDS writes lane-consecutive -> conflict-free)
    #pragma unroll
    for (int i2 = 0; i2 < 4; ++i2) {
        int idx = dm * 4 + i2;           // 0..63 = (d, m4)
        int d = idx >> 1, m4 = idx & 1;
        U4[(d * 2 + m4) * 64 + lane] =
            *(const float4*)(metaw + ((lane * 32 + d) * MM + m4 * 4));
    }
    if (dm < 8) {
        int s0 = lane * 32 + dm * 4;
        float4 bv = *(const float4*)(base  + s0);
        float4 mv = *(const float4*)(metab + s0);
        B1q[dm * 64 + lane] = make_float4(bv.x + mv.x, bv.y + mv.y, bv.z + mv.z, bv.w + mv.w);
    } else if (dm < 10) {
        int m4 = dm - 8;
        Ub1[m4 * 64 + lane] = *(const float4*)(metaw + ((2048 + lane) * MM + m4 * 4));
    } else if (dm < 12) {
        int m4 = dm - 10;
        U2q[m4 * 64 + lane] = *(const float4*)(metaw + ((2112 + lane) * MM + m4 * 4));
    } else if (dm == 12) {
        B1b[lane] = base[2048 + lane] + metab[2048 + lane];
    } else if (dm == 13) {
        B2b[lane] = base[2112 + lane] + metab[2112 + lane];
    }
    __syncthreads();

    // ---- this wave's batch of 8 samples
    const int n0 = blockIdx.x * 128 + dm * KB;

    // x for the batch: flat f = i*32+d over [0,256) -> reg r=f>>6 (=i>>1), readlane idx f&63
    float xr[4];
    #pragma unroll
    for (int r = 0; r < 4; ++r) xr[r] = x[n0 * DD + r * 64 + lane];  // coalesced

    float4 g0[KB], g1[KB];
    float  c0[KB];
    #pragma unroll
    for (int i = 0; i < KB; ++i) {
        g0[i] = make_float4(0.f, 0.f, 0.f, 0.f);
        g1[i] = make_float4(0.f, 0.f, 0.f, 0.f);
        c0[i] = 0.f;
    }

    for (int dq = 0; dq < 8; ++dq) {
        float4 bq = B1q[dq * 64 + lane];
        #pragma unroll
        for (int dd = 0; dd < 4; ++dd) {
            int d = dq * 4 + dd;
            float4 u0 = U4[(d * 2 + 0) * 64 + lane];   // conflict-free b128
            float4 u1 = U4[(d * 2 + 1) * 64 + lane];
            float bs = (dd == 0) ? bq.x : (dd == 1) ? bq.y : (dd == 2) ? bq.z : bq.w;
            #pragma unroll
            for (int i = 0; i < KB; ++i) {
                int lidx = (i & 1) * 32 + d;           // uniform (SGPR) lane index
                float xv = __uint_as_float(
                    __builtin_amdgcn_readlane(__float_as_uint(xr[i >> 1]), lidx));
                c0[i]   = fmaf(xv, bs,   c0[i]);
                g0[i].x = fmaf(xv, u0.x, g0[i].x);
                g0[i].y = fmaf(xv, u0.y, g0[i].y);
                g0[i].z = fmaf(xv, u0.z, g0[i].z);
                g0[i].w = fmaf(xv, u0.w, g0[i].w);
                g1[i].x = fmaf(xv, u1.x, g1[i].x);
                g1[i].y = fmaf(xv, u1.y, g1[i].y);
                g1[i].z = fmaf(xv, u1.z, g1[i].z);
                g1[i].w = fmaf(xv, u1.w, g1[i].w);
            }
        }
    }

    // ---- epilogue (weights hoisted out of the sample loop)
    float4 ub1a = Ub1[0 * 64 + lane], ub1b = Ub1[1 * 64 + lane];
    float4 u2a  = U2q[0 * 64 + lane], u2b  = U2q[1 * 64 + lane];
    float  b1base = B1b[lane], b2base = B2b[lane];
    float4 w2m0 = *(const float4*)(metaw + 2176 * MM);
    float4 w2m1 = *(const float4*)(metaw + 2176 * MM + 4);
    float  b2c  = base[2176] + metab[2176];

    #pragma unroll
    for (int i = 0; i < KB; ++i) {
        int n = n0 + i;
        int t = ticker[n];                       // wave-uniform broadcast load
        float mi[8];
        #pragma unroll
        for (int m = 0; m < 8; ++m) mi[m] = mesa[m * TT + t];  // L1-resident (32 KB)

        float b1 = b1base
                 + mi[0] * ub1a.x + mi[1] * ub1a.y + mi[2] * ub1a.z + mi[3] * ub1a.w
                 + mi[4] * ub1b.x + mi[5] * ub1b.y + mi[6] * ub1b.z + mi[7] * ub1b.w;
        float h = c0[i] + b1
                 + mi[0] * g0[i].x + mi[1] * g0[i].y + mi[2] * g0[i].z + mi[3] * g0[i].w
                 + mi[4] * g1[i].x + mi[5] * g1[i].y + mi[6] * g1[i].z + mi[7] * g1[i].w;
        h = fmaxf(h, 0.f);
        float w2 = b2base
                 + mi[0] * u2a.x + mi[1] * u2a.y + mi[2] * u2a.z + mi[3] * u2a.w
                 + mi[4] * u2b.x + mi[5] * u2b.y + mi[6] * u2b.z + mi[7] * u2b.w;
        float p = h * w2;
        #pragma unroll
        for (int off = 32; off >= 1; off >>= 1)
            p += __shfl_down(p, off, 64);
        if (lane == 0) {
            float b2 = b2c
                 + mi[0] * w2m0.x + mi[1] * w2m0.y + mi[2] * w2m0.z + mi[3] * w2m0.w
                 + mi[4] * w2m1.x + mi[5] * w2m1.y + mi[6] * w2m1.z + mi[7] * w2m1.w;
            out[n] = p + b2;
        }
    }
}

extern "C" void kernel_launch(void* const* d_in, const int* in_sizes, int n_in,
                              void* d_out, int out_size, void* d_ws, size_t ws_size,
                              hipStream_t stream) {
    const float* x      = (const float*)d_in[0];
    const int*   ticker = (const int*)  d_in[1];
    const float* mesa   = (const float*)d_in[2];
    const float* metaw  = (const float*)d_in[3];
    const float* metab  = (const float*)d_in[4];
    const float* base   = (const float*)d_in[5];
    float* out = (float*)d_out;

    // 256 blocks x 16 waves x 8 samples = 32768
    fused_kernel<<<256, 1024, 0, stream>>>(x, ticker, mesa, metaw, metab, base, out);
}